// Round 8
// baseline (2851.878 us; speedup 1.0000x reference)
//
#include <hip/hip_runtime.h>
#include <math.h>

#define NSTAGES 4
#define NCB     1024
#define SK      4096   // NSTAGES*NCB
#define D       256
#define BEAM_W  4
#define NB      4096   // N samples

// ---------------- LLVM-vectorized reduce over 256 f32, VF=8, IC=4:
// 32 chains r_l += t[32*i + l] (i=0..7 ascending); parts folded left:
// w_j = ((r_j + r_{8+j}) + r_{16+j}) + r_{24+j};  then shuffle-halving:
// s_j = w_j + w_{j+4};  t0 = s0+s2, t1 = s1+s3;  res = t0+t1.
template <typename F>
__device__ __forceinline__ float xw84(F v) {
  float r[32];
#pragma unroll
  for (int l = 0; l < 32; ++l) r[l] = v(l);
  for (int i = 32; i < 256; i += 32)
#pragma unroll
    for (int l = 0; l < 32; ++l) r[l] = __fadd_rn(r[l], v(i + l));
  float w[8];
#pragma unroll
  for (int j = 0; j < 8; ++j)
    w[j] = __fadd_rn(__fadd_rn(__fadd_rn(r[j], r[8 + j]), r[16 + j]), r[24 + j]);
  float s0 = __fadd_rn(w[0], w[4]);
  float s1 = __fadd_rn(w[1], w[5]);
  float s2 = __fadd_rn(w[2], w[6]);
  float s3 = __fadd_rn(w[3], w[7]);
  float t0 = __fadd_rn(s0, s2);
  float t1 = __fadd_rn(s1, s3);
  return __fadd_rn(t0, t1);
}

// ---------------- cb2[j] = sum(cb[j]**2)
__global__ __launch_bounds__(256) void cb2_pw(const float* __restrict__ cb,
                                              float* __restrict__ cb2) {
  int row = blockIdx.x * 256 + threadIdx.x;
  if (row >= SK) return;
  const float* c = cb + (size_t)row * D;
  cb2[row] = xw84([&](int d) { float t = c[d]; return __fmul_rn(t, t); });
}

// ---------------- Srow[s] = sum(x[s]**2)
__global__ __launch_bounds__(256) void s0_pw(const float* __restrict__ x,
                                             float* __restrict__ Srow) {
  int row = blockIdx.x * 256 + threadIdx.x;
  if (row >= NB) return;
  const float* xr = x + (size_t)row * D;
  Srow[row] = xw84([&](int d) { float t = xr[d]; return __fmul_rn(t, t); });
}

// ---------------- remainder rows + their sum-of-squares
// row = s*4+b ; rem = fl(x - fl((it+1)*c_slot)) ; Srow[row] = reduce(rem^2)
__global__ __launch_bounds__(256) void rem_pw(const float* __restrict__ x,
                                              const float* __restrict__ cb,
                                              const int* __restrict__ tuples,
                                              int it,
                                              float* __restrict__ rem,
                                              float* __restrict__ Srow) {
  int row = blockIdx.x * 256 + threadIdx.x;
  if (row >= NB * BEAM_W) return;
  int s = row >> 2;
  int slot = tuples[row * NSTAGES + it];
  const float* xr = x + (size_t)s * D;
  const float* cr = cb + (size_t)slot * D;
  const float mf = (float)(it + 1);
  float* rr = rem + (size_t)row * D;
  for (int d = 0; d < D; ++d)
    rr[d] = __fsub_rn(xr[d], __fmul_rn(mf, cr[d]));
  Srow[row] = xw84([&](int d) {
    float t = __fsub_rn(xr[d], __fmul_rn(mf, cr[d]));
    return __fmul_rn(t, t);
  });
}

// ---------------- C[r, j] = sum_k A[r,k]*cb[j,k], STRICT ascending-k fmaf chain
// (bit-matches Eigen/oneDNN/OpenBLAS gemm microkernels: one acc, fma, k=0..255)
__global__ __launch_bounds__(256) void gemm_seq(const float* __restrict__ A,
                                                const float* __restrict__ B,
                                                float* __restrict__ C) {
  __shared__ float As[64][65];
  __shared__ float Bs[64][65];
  const int tx = threadIdx.x & 15;
  const int ty = threadIdx.x >> 4;
  const int row0 = blockIdx.y * 64;
  const int col0 = blockIdx.x * 64;
  float acc[4][4];
#pragma unroll
  for (int i = 0; i < 4; ++i)
#pragma unroll
    for (int j = 0; j < 4; ++j) acc[i][j] = 0.0f;

  for (int kt = 0; kt < D; kt += 64) {
#pragma unroll
    for (int l = 0; l < 4; ++l) {
      int t  = threadIdx.x + l * 256;
      int r  = t >> 4;
      int c4 = (t & 15) * 4;
      float4 va = *(const float4*)&A[(size_t)(row0 + r) * D + kt + c4];
      As[r][c4 + 0] = va.x; As[r][c4 + 1] = va.y; As[r][c4 + 2] = va.z; As[r][c4 + 3] = va.w;
      float4 vb = *(const float4*)&B[(size_t)(col0 + r) * D + kt + c4];
      Bs[r][c4 + 0] = vb.x; Bs[r][c4 + 1] = vb.y; Bs[r][c4 + 2] = vb.z; Bs[r][c4 + 3] = vb.w;
    }
    __syncthreads();
#pragma unroll 8
    for (int k = 0; k < 64; ++k) {   // ascending k only — do not reorder
      float a[4], b[4];
#pragma unroll
      for (int i = 0; i < 4; ++i) a[i] = As[ty * 4 + i][k];
#pragma unroll
      for (int i = 0; i < 4; ++i) b[i] = Bs[tx * 4 + i][k];
#pragma unroll
      for (int i = 0; i < 4; ++i)
#pragma unroll
        for (int j = 0; j < 4; ++j)
          acc[i][j] = __fmaf_rn(a[i], b[j], acc[i][j]);
    }
    __syncthreads();
  }
#pragma unroll
  for (int i = 0; i < 4; ++i)
#pragma unroll
    for (int j = 0; j < 4; ++j)
      C[(size_t)(row0 + ty * 4 + i) * SK + col0 + tx * 4 + j] = acc[i][j];
}

// ---------------- top-4 scan: key_j = fl(fl(S - fl(2*M_j)) + cb2_j), bans -> inf
// TIE-BREAK: equal keys -> LOWEST index (lax.top_k stable semantics).
__global__ __launch_bounds__(256) void scan_top4(const float* __restrict__ Mbuf,
                                                 const float* __restrict__ Srow,
                                                 const float* __restrict__ cb2,
                                                 const int* __restrict__ tuples,
                                                 int it, int row0, int isStep0,
                                                 int* __restrict__ tuples_out,
                                                 int* __restrict__ cand_out) {
  const int row = row0 + blockIdx.x;
  const int tid = threadIdx.x;
  const int wv = tid >> 6, lane = tid & 63;
  __shared__ float keys[SK];
  __shared__ float wkey[4];
  __shared__ int   widx[4];
  __shared__ int   res[4];
  __shared__ int   bannedSh;
  const float FINF = __builtin_huge_valf();

  if (tid == 0) {
    int banned = 0;
    if (!isStep0)
      for (int a = 0; a <= it; ++a) banned |= 1 << (tuples[row * NSTAGES + a] >> 10);
    bannedSh = banned;
  }
  __syncthreads();
  const int banned = bannedSh;
  const float S = Srow[row];
  const float* Mr = Mbuf + (size_t)blockIdx.x * SK;
  for (int j = tid; j < SK; j += 256) {
    float key;
    if ((banned >> (j >> 10)) & 1) key = FINF;
    else key = __fadd_rn(__fsub_rn(S, __fmul_rn(2.0f, Mr[j])), cb2[j]);
    keys[j] = key;
  }
  __syncthreads();

  for (int r = 0; r < 4; ++r) {
    float bk = FINF;
    int   bi = 0x7fffffff;
    for (int l = 0; l < 16; ++l) {
      int j = tid + (l << 8);
      float k = keys[j];
      if (k < bk || (k == bk && j < bi)) { bk = k; bi = j; }
    }
    for (int off = 32; off; off >>= 1) {
      float k2 = __shfl_down(bk, off);
      int   i2 = __shfl_down(bi, off);
      if (k2 < bk || (k2 == bk && i2 < bi)) { bk = k2; bi = i2; }
    }
    if (lane == 0) { wkey[wv] = bk; widx[wv] = bi; }
    __syncthreads();
    if (tid == 0) {
      float fk = wkey[0]; int fi = widx[0];
      for (int w = 1; w < 4; ++w)
        if (wkey[w] < fk || (wkey[w] == fk && widx[w] < fi)) { fk = wkey[w]; fi = widx[w]; }
      res[r] = fi;
      keys[fi] = FINF;   // exclude for next pass
    }
    __syncthreads();
  }
  if (tid < 4) {
    if (isStep0) tuples_out[(row * BEAM_W + tid) * NSTAGES + 0] = res[tid];
    else         cand_out[row * BEAM_W + tid] = res[tid];
  }
}

// ---------------- expand 16 tuples, mse via VF8/IC4 reduce, select
// sel ties -> LOWEST p; final argmin ties -> LOWEST p.
__global__ __launch_bounds__(256) void mse_select(const float* __restrict__ x,
                                                  const float* __restrict__ cb,
                                                  const int* __restrict__ cand,
                                                  int it,
                                                  int* __restrict__ tuples,
                                                  int* __restrict__ best) {
  const int s = blockIdx.x, tid = threadIdx.x;
  const int wv = tid >> 6, lane = tid & 63;
  __shared__ float buf[4][256];
  __shared__ float rr[4][32];
  __shared__ float msek[16];
  __shared__ int   primes[16][NSTAGES];
  const int L = it + 2;

  for (int pi = 0; pi < 4; ++pi) {
    const int p = wv * 4 + pi;
    const int b = p >> 2, c = p & 3;
    int tpl[NSTAGES];
    for (int a = 0; a < NSTAGES; ++a) tpl[a] = tuples[(s * BEAM_W + b) * NSTAGES + a];
    tpl[it + 1] = cand[(s * BEAM_W + b) * BEAM_W + c];
    if (lane == 0)
      for (int a = 0; a < NSTAGES; ++a) primes[p][a] = tpl[a];
    for (int d = lane; d < D; d += 64) {
      // q = left-assoc slot-order f32 sum (non-minor-axis reduce: sequential)
      float q = cb[(size_t)tpl[0] * D + d];
      for (int a = 1; a < L; ++a) q = __fadd_rn(q, cb[(size_t)tpl[a] * D + d]);
      float v = __fsub_rn(x[(size_t)s * D + d], q);
      buf[wv][d] = __fmul_rn(v, v);
    }
    __syncthreads();
    if (lane < 32) {   // 32 chains: r_l = sum_i t[32*i + l], i ascending
      float r = buf[wv][lane];
      for (int i = 32; i < 256; i += 32) r = __fadd_rn(r, buf[wv][i + lane]);
      rr[wv][lane] = r;
    }
    __syncthreads();
    if (lane == 0) {
      float w[8];
#pragma unroll
      for (int j = 0; j < 8; ++j)
        w[j] = __fadd_rn(__fadd_rn(__fadd_rn(rr[wv][j], rr[wv][8 + j]), rr[wv][16 + j]),
                         rr[wv][24 + j]);
      float s0 = __fadd_rn(w[0], w[4]);
      float s1 = __fadd_rn(w[1], w[5]);
      float s2 = __fadd_rn(w[2], w[6]);
      float s3 = __fadd_rn(w[3], w[7]);
      float t0 = __fadd_rn(s0, s2);
      float t1 = __fadd_rn(s1, s3);
      float S2 = __fadd_rn(t0, t1);
      msek[p] = __fmul_rn(S2, 0.00390625f);  // /256 exact
    }
    __syncthreads();
  }

  if (tid == 0) {
    if (it < NSTAGES - 2) {
      bool taken[16] = {false};
      int  newt[BEAM_W][NSTAGES];
      for (int r = 0; r < BEAM_W; ++r) {
        int bp = -1; float bk = 0.0f;
        for (int p = 0; p < 16; ++p) {
          if (taken[p]) continue;
          if (bp < 0 || msek[p] < bk) { bk = msek[p]; bp = p; }  // strict <: lowest p wins ties
        }
        taken[bp] = true;
        for (int a = 0; a < NSTAGES; ++a) newt[r][a] = primes[bp][a];
      }
      for (int r = 0; r < BEAM_W; ++r)
        for (int a = 0; a < NSTAGES; ++a) tuples[(s * BEAM_W + r) * NSTAGES + a] = newt[r][a];
    } else {
      int bp = 0; float bk = msek[0];
      for (int p = 1; p < 16; ++p)
        if (msek[p] < bk) { bk = msek[p]; bp = p; }   // argmin: first lowest
      for (int a = 0; a < NSTAGES; ++a) best[s * NSTAGES + a] = primes[bp][a];
    }
  }
}

// ---------------- zero the 'used' region of d_out
__global__ void zero_used(float* __restrict__ u) {
  int t = blockIdx.x * 256 + threadIdx.x;
  if (t < SK) u[t] = 0.0f;
}

// ---------------- epilogue: nsvq (or quantized) + used bitmap
__global__ __launch_bounds__(256) void finalize_kernel(const float* __restrict__ x,
                                                       const float* __restrict__ cb,
                                                       const float* __restrict__ rvec,
                                                       const int* __restrict__ best,
                                                       const int* __restrict__ tmode,
                                                       float* __restrict__ out) {
  const int i = blockIdx.x;
  const int t = threadIdx.x;
  __shared__ double s1[256], s2[256];
  const int b0 = best[i * 4 + 0], b1 = best[i * 4 + 1];
  const int b2 = best[i * 4 + 2], b3 = best[i * 4 + 3];
  float q = ((cb[(size_t)b0 * D + t] + cb[(size_t)b1 * D + t]) + cb[(size_t)b2 * D + t]) +
            cb[(size_t)b3 * D + t];
  float xv = x[(size_t)i * D + t];
  float rv = rvec[(size_t)i * D + t];
  float df = xv - q;
  s1[t] = (double)df * (double)df;
  s2[t] = (double)rv * (double)rv;
  __syncthreads();
  for (int off = 128; off; off >>= 1) {
    if (t < off) { s1[t] += s1[t + off]; s2[t] += s2[t + off]; }
    __syncthreads();
  }
  float nh = sqrtf((float)s1[0]);
  float nr = sqrtf((float)s2[0]);
  float ratio = nh / nr + 1e-12f;
  out[(size_t)i * D + t] = (*tmode != 0) ? (xv + ratio * rv) : q;
  if (t < 4) out[(size_t)NB * D + best[i * 4 + t]] = 1.0f;
}

// ----------------------------------------------------------------
extern "C" void kernel_launch(void* const* d_in, const int* in_sizes, int n_in,
                              void* d_out, int out_size, void* d_ws, size_t ws_size,
                              hipStream_t stream) {
  const float* x   = (const float*)d_in[0];
  const float* cb  = (const float*)d_in[1];
  const float* rv  = (const float*)d_in[2];
  const int*   tm  = (const int*)d_in[3];
  float*       out = (float*)d_out;

  const size_t M_BYTES    = (size_t)NB * SK * sizeof(float);
  const size_t REM_BYTES  = (size_t)NB * BEAM_W * D * sizeof(float);
  const size_t S_BYTES    = (size_t)NB * BEAM_W * sizeof(float);
  const size_t CB2_BYTES  = (size_t)SK * sizeof(float);
  const size_t TUP_BYTES  = (size_t)NB * BEAM_W * NSTAGES * sizeof(int);
  const size_t CAND_BYTES = (size_t)NB * BEAM_W * BEAM_W * sizeof(int);
  const size_t BEST_BYTES = (size_t)NB * NSTAGES * sizeof(int);
  if (ws_size < M_BYTES + REM_BYTES + S_BYTES + CB2_BYTES + TUP_BYTES + CAND_BYTES + BEST_BYTES)
    return;

  char* ws = (char*)d_ws;
  float* Mbuf = (float*)ws;                    ws += M_BYTES;
  float* rem  = (float*)ws;                    ws += REM_BYTES;
  float* Srow = (float*)ws;                    ws += S_BYTES;
  float* cb2  = (float*)ws;                    ws += CB2_BYTES;
  int*   tup  = (int*)ws;                      ws += TUP_BYTES;
  int*   cand = (int*)ws;                      ws += CAND_BYTES;
  int*   best = (int*)ws;

  cb2_pw<<<SK / 256, 256, 0, stream>>>(cb, cb2);
  s0_pw<<<NB / 256, 256, 0, stream>>>(x, Srow);

  dim3 gg(SK / 64, NB / 64);
  gemm_seq<<<gg, 256, 0, stream>>>(x, cb, Mbuf);
  scan_top4<<<NB, 256, 0, stream>>>(Mbuf, Srow, cb2, tup, 0, 0, 1, tup, cand);

  for (int it = 0; it < NSTAGES - 1; ++it) {
    rem_pw<<<(NB * BEAM_W) / 256, 256, 0, stream>>>(x, cb, tup, it, rem, Srow);
    for (int c = 0; c < 4; ++c) {
      gemm_seq<<<gg, 256, 0, stream>>>(rem + (size_t)c * NB * D, cb, Mbuf);
      scan_top4<<<NB, 256, 0, stream>>>(Mbuf, Srow, cb2, tup, it, c * NB, 0, tup, cand);
    }
    mse_select<<<NB, 256, 0, stream>>>(x, cb, cand, it, tup, best);
  }

  zero_used<<<SK / 256, 256, 0, stream>>>(out + (size_t)NB * D);
  finalize_kernel<<<NB, 256, 0, stream>>>(x, cb, rv, best, tm, out);
}

// Round 9
// 2122.095 us; speedup vs baseline: 1.3439x; 1.3439x over previous
//
#include <hip/hip_runtime.h>
#include <math.h>

#define NSTAGES 4
#define NCB     1024
#define SK      4096   // NSTAGES*NCB
#define D       256
#define BEAM_W  4
#define NB      4096   // N samples

// ---------------- LLVM-vectorized reduce over 256 f32, VF=8, IC=4 (FROZEN - bit-exact vs ref)
template <typename F>
__device__ __forceinline__ float xw84(F v) {
  float r[32];
#pragma unroll
  for (int l = 0; l < 32; ++l) r[l] = v(l);
  for (int i = 32; i < 256; i += 32)
#pragma unroll
    for (int l = 0; l < 32; ++l) r[l] = __fadd_rn(r[l], v(i + l));
  float w[8];
#pragma unroll
  for (int j = 0; j < 8; ++j)
    w[j] = __fadd_rn(__fadd_rn(__fadd_rn(r[j], r[8 + j]), r[16 + j]), r[24 + j]);
  float s0 = __fadd_rn(w[0], w[4]);
  float s1 = __fadd_rn(w[1], w[5]);
  float s2 = __fadd_rn(w[2], w[6]);
  float s3 = __fadd_rn(w[3], w[7]);
  float t0 = __fadd_rn(s0, s2);
  float t1 = __fadd_rn(s1, s3);
  return __fadd_rn(t0, t1);
}

// ---------------- cb2[j] = sum(cb[j]**2)
__global__ __launch_bounds__(256) void cb2_pw(const float* __restrict__ cb,
                                              float* __restrict__ cb2) {
  int row = blockIdx.x * 256 + threadIdx.x;
  if (row >= SK) return;
  const float* c = cb + (size_t)row * D;
  cb2[row] = xw84([&](int d) { float t = c[d]; return __fmul_rn(t, t); });
}

// ---------------- Srow[s] = sum(x[s]**2)
__global__ __launch_bounds__(256) void s0_pw(const float* __restrict__ x,
                                             float* __restrict__ Srow) {
  int row = blockIdx.x * 256 + threadIdx.x;
  if (row >= NB) return;
  const float* xr = x + (size_t)row * D;
  Srow[row] = xw84([&](int d) { float t = xr[d]; return __fmul_rn(t, t); });
}

// ---------------- remainder rows + their sum-of-squares (FROZEN numerics)
__global__ __launch_bounds__(256) void rem_pw(const float* __restrict__ x,
                                              const float* __restrict__ cb,
                                              const int* __restrict__ tuples,
                                              int it,
                                              float* __restrict__ rem,
                                              float* __restrict__ Srow) {
  int row = blockIdx.x * 256 + threadIdx.x;
  if (row >= NB * BEAM_W) return;
  int s = row >> 2;
  int slot = tuples[row * NSTAGES + it];
  const float* xr = x + (size_t)s * D;
  const float* cr = cb + (size_t)slot * D;
  const float mf = (float)(it + 1);
  float* rr = rem + (size_t)row * D;
  for (int d = 0; d < D; ++d)
    rr[d] = __fsub_rn(xr[d], __fmul_rn(mf, cr[d]));
  Srow[row] = xw84([&](int d) {
    float t = __fsub_rn(xr[d], __fmul_rn(mf, cr[d]));
    return __fmul_rn(t, t);
  });
}

// ---------------- C[r, j] = sum_k A[r,k]*cb[j,k], STRICT ascending-k fmaf chain.
// 128x128 block tile, 8x8 per-thread tile, k-major LDS so compute reads are
// ds_read_b128. Accumulation order per output element unchanged (bit-exact).
__global__ __launch_bounds__(256) void gemm_seq(const float* __restrict__ A,
                                                const float* __restrict__ B,
                                                float* __restrict__ C) {
  __shared__ float As[32][128];   // k-major
  __shared__ float Bs[32][128];
  const int tx = threadIdx.x & 15;   // col group (0..15) -> 8 cols each
  const int ty = threadIdx.x >> 4;   // row group (0..15) -> 8 rows each
  const int row0 = blockIdx.y * 128;
  const int col0 = blockIdx.x * 128;
  float acc[8][8];
#pragma unroll
  for (int i = 0; i < 8; ++i)
#pragma unroll
    for (int j = 0; j < 8; ++j) acc[i][j] = 0.0f;

  for (int kt = 0; kt < D; kt += 32) {
    // stage: 128 rows x 32 k each for A and B; 1024 float4 per matrix, 4 per thread
#pragma unroll
    for (int l = 0; l < 4; ++l) {
      int t  = threadIdx.x + l * 256;   // 0..1023
      int r  = t & 127;                 // row within tile
      int kc = (t >> 7) * 4;            // k-chunk base: 0,4,...,28
      float4 va = *(const float4*)&A[(size_t)(row0 + r) * D + kt + kc];
      As[kc + 0][r] = va.x; As[kc + 1][r] = va.y; As[kc + 2][r] = va.z; As[kc + 3][r] = va.w;
      float4 vb = *(const float4*)&B[(size_t)(col0 + r) * D + kt + kc];
      Bs[kc + 0][r] = vb.x; Bs[kc + 1][r] = vb.y; Bs[kc + 2][r] = vb.z; Bs[kc + 3][r] = vb.w;
    }
    __syncthreads();
#pragma unroll 8
    for (int k = 0; k < 32; ++k) {   // ascending k only — do not reorder
      float a[8], b[8];
      *(float4*)&a[0] = *(const float4*)&As[k][ty * 8 + 0];
      *(float4*)&a[4] = *(const float4*)&As[k][ty * 8 + 4];
      *(float4*)&b[0] = *(const float4*)&Bs[k][tx * 8 + 0];
      *(float4*)&b[4] = *(const float4*)&Bs[k][tx * 8 + 4];
#pragma unroll
      for (int i = 0; i < 8; ++i)
#pragma unroll
        for (int j = 0; j < 8; ++j)
          acc[i][j] = __fmaf_rn(a[i], b[j], acc[i][j]);
    }
    __syncthreads();
  }
#pragma unroll
  for (int i = 0; i < 8; ++i) {
    float* cp = &C[(size_t)(row0 + ty * 8 + i) * SK + col0 + tx * 8];
    *(float4*)&cp[0] = make_float4(acc[i][0], acc[i][1], acc[i][2], acc[i][3]);
    *(float4*)&cp[4] = make_float4(acc[i][4], acc[i][5], acc[i][6], acc[i][7]);
  }
}

// ---------------- top-4 scan: key_j = fl(fl(S - fl(2*M_j)) + cb2_j), bans -> inf
// TIE-BREAK: equal keys -> LOWEST index (FROZEN)
__global__ __launch_bounds__(256) void scan_top4(const float* __restrict__ Mbuf,
                                                 const float* __restrict__ Srow,
                                                 const float* __restrict__ cb2,
                                                 const int* __restrict__ tuples,
                                                 int it, int row0, int isStep0,
                                                 int* __restrict__ tuples_out,
                                                 int* __restrict__ cand_out) {
  const int row = row0 + blockIdx.x;
  const int tid = threadIdx.x;
  const int wv = tid >> 6, lane = tid & 63;
  __shared__ float keys[SK];
  __shared__ float wkey[4];
  __shared__ int   widx[4];
  __shared__ int   res[4];
  __shared__ int   bannedSh;
  const float FINF = __builtin_huge_valf();

  if (tid == 0) {
    int banned = 0;
    if (!isStep0)
      for (int a = 0; a <= it; ++a) banned |= 1 << (tuples[row * NSTAGES + a] >> 10);
    bannedSh = banned;
  }
  __syncthreads();
  const int banned = bannedSh;
  const float S = Srow[row];
  const float* Mr = Mbuf + (size_t)blockIdx.x * SK;
  for (int j = tid; j < SK; j += 256) {
    float key;
    if ((banned >> (j >> 10)) & 1) key = FINF;
    else key = __fadd_rn(__fsub_rn(S, __fmul_rn(2.0f, Mr[j])), cb2[j]);
    keys[j] = key;
  }
  __syncthreads();

  for (int r = 0; r < 4; ++r) {
    float bk = FINF;
    int   bi = 0x7fffffff;
    for (int l = 0; l < 16; ++l) {
      int j = tid + (l << 8);
      float k = keys[j];
      if (k < bk || (k == bk && j < bi)) { bk = k; bi = j; }
    }
    for (int off = 32; off; off >>= 1) {
      float k2 = __shfl_down(bk, off);
      int   i2 = __shfl_down(bi, off);
      if (k2 < bk || (k2 == bk && i2 < bi)) { bk = k2; bi = i2; }
    }
    if (lane == 0) { wkey[wv] = bk; widx[wv] = bi; }
    __syncthreads();
    if (tid == 0) {
      float fk = wkey[0]; int fi = widx[0];
      for (int w = 1; w < 4; ++w)
        if (wkey[w] < fk || (wkey[w] == fk && widx[w] < fi)) { fk = wkey[w]; fi = widx[w]; }
      res[r] = fi;
      keys[fi] = FINF;   // exclude for next pass
    }
    __syncthreads();
  }
  if (tid < 4) {
    if (isStep0) tuples_out[(row * BEAM_W + tid) * NSTAGES + 0] = res[tid];
    else         cand_out[row * BEAM_W + tid] = res[tid];
  }
}

// ---------------- expand 16 tuples, mse via VF8/IC4 reduce, select (FROZEN numerics)
__global__ __launch_bounds__(256) void mse_select(const float* __restrict__ x,
                                                  const float* __restrict__ cb,
                                                  const int* __restrict__ cand,
                                                  int it,
                                                  int* __restrict__ tuples,
                                                  int* __restrict__ best) {
  const int s = blockIdx.x, tid = threadIdx.x;
  const int wv = tid >> 6, lane = tid & 63;
  __shared__ float buf[4][256];
  __shared__ float rr[4][32];
  __shared__ float msek[16];
  __shared__ int   primes[16][NSTAGES];
  const int L = it + 2;

  for (int pi = 0; pi < 4; ++pi) {
    const int p = wv * 4 + pi;
    const int b = p >> 2, c = p & 3;
    int tpl[NSTAGES];
    for (int a = 0; a < NSTAGES; ++a) tpl[a] = tuples[(s * BEAM_W + b) * NSTAGES + a];
    tpl[it + 1] = cand[(s * BEAM_W + b) * BEAM_W + c];
    if (lane == 0)
      for (int a = 0; a < NSTAGES; ++a) primes[p][a] = tpl[a];
    for (int d = lane; d < D; d += 64) {
      float q = cb[(size_t)tpl[0] * D + d];
      for (int a = 1; a < L; ++a) q = __fadd_rn(q, cb[(size_t)tpl[a] * D + d]);
      float v = __fsub_rn(x[(size_t)s * D + d], q);
      buf[wv][d] = __fmul_rn(v, v);
    }
    __syncthreads();
    if (lane < 32) {
      float r = buf[wv][lane];
      for (int i = 32; i < 256; i += 32) r = __fadd_rn(r, buf[wv][i + lane]);
      rr[wv][lane] = r;
    }
    __syncthreads();
    if (lane == 0) {
      float w[8];
#pragma unroll
      for (int j = 0; j < 8; ++j)
        w[j] = __fadd_rn(__fadd_rn(__fadd_rn(rr[wv][j], rr[wv][8 + j]), rr[wv][16 + j]),
                         rr[wv][24 + j]);
      float s0 = __fadd_rn(w[0], w[4]);
      float s1 = __fadd_rn(w[1], w[5]);
      float s2 = __fadd_rn(w[2], w[6]);
      float s3 = __fadd_rn(w[3], w[7]);
      float t0 = __fadd_rn(s0, s2);
      float t1 = __fadd_rn(s1, s3);
      float S2 = __fadd_rn(t0, t1);
      msek[p] = __fmul_rn(S2, 0.00390625f);  // /256 exact
    }
    __syncthreads();
  }

  if (tid == 0) {
    if (it < NSTAGES - 2) {
      bool taken[16] = {false};
      int  newt[BEAM_W][NSTAGES];
      for (int r = 0; r < BEAM_W; ++r) {
        int bp = -1; float bk = 0.0f;
        for (int p = 0; p < 16; ++p) {
          if (taken[p]) continue;
          if (bp < 0 || msek[p] < bk) { bk = msek[p]; bp = p; }  // strict <: lowest p wins ties
        }
        taken[bp] = true;
        for (int a = 0; a < NSTAGES; ++a) newt[r][a] = primes[bp][a];
      }
      for (int r = 0; r < BEAM_W; ++r)
        for (int a = 0; a < NSTAGES; ++a) tuples[(s * BEAM_W + r) * NSTAGES + a] = newt[r][a];
    } else {
      int bp = 0; float bk = msek[0];
      for (int p = 1; p < 16; ++p)
        if (msek[p] < bk) { bk = msek[p]; bp = p; }   // argmin: first lowest
      for (int a = 0; a < NSTAGES; ++a) best[s * NSTAGES + a] = primes[bp][a];
    }
  }
}

// ---------------- zero the 'used' region of d_out
__global__ void zero_used(float* __restrict__ u) {
  int t = blockIdx.x * 256 + threadIdx.x;
  if (t < SK) u[t] = 0.0f;
}

// ---------------- epilogue: nsvq (or quantized) + used bitmap
__global__ __launch_bounds__(256) void finalize_kernel(const float* __restrict__ x,
                                                       const float* __restrict__ cb,
                                                       const float* __restrict__ rvec,
                                                       const int* __restrict__ best,
                                                       const int* __restrict__ tmode,
                                                       float* __restrict__ out) {
  const int i = blockIdx.x;
  const int t = threadIdx.x;
  __shared__ double s1[256], s2[256];
  const int b0 = best[i * 4 + 0], b1 = best[i * 4 + 1];
  const int b2 = best[i * 4 + 2], b3 = best[i * 4 + 3];
  float q = ((cb[(size_t)b0 * D + t] + cb[(size_t)b1 * D + t]) + cb[(size_t)b2 * D + t]) +
            cb[(size_t)b3 * D + t];
  float xv = x[(size_t)i * D + t];
  float rv = rvec[(size_t)i * D + t];
  float df = xv - q;
  s1[t] = (double)df * (double)df;
  s2[t] = (double)rv * (double)rv;
  __syncthreads();
  for (int off = 128; off; off >>= 1) {
    if (t < off) { s1[t] += s1[t + off]; s2[t] += s2[t + off]; }
    __syncthreads();
  }
  float nh = sqrtf((float)s1[0]);
  float nr = sqrtf((float)s2[0]);
  float ratio = nh / nr + 1e-12f;
  out[(size_t)i * D + t] = (*tmode != 0) ? (xv + ratio * rv) : q;
  if (t < 4) out[(size_t)NB * D + best[i * 4 + t]] = 1.0f;
}

// ----------------------------------------------------------------
extern "C" void kernel_launch(void* const* d_in, const int* in_sizes, int n_in,
                              void* d_out, int out_size, void* d_ws, size_t ws_size,
                              hipStream_t stream) {
  const float* x   = (const float*)d_in[0];
  const float* cb  = (const float*)d_in[1];
  const float* rv  = (const float*)d_in[2];
  const int*   tm  = (const int*)d_in[3];
  float*       out = (float*)d_out;

  const size_t M_BYTES    = (size_t)NB * SK * sizeof(float);
  const size_t REM_BYTES  = (size_t)NB * BEAM_W * D * sizeof(float);
  const size_t S_BYTES    = (size_t)NB * BEAM_W * sizeof(float);
  const size_t CB2_BYTES  = (size_t)SK * sizeof(float);
  const size_t TUP_BYTES  = (size_t)NB * BEAM_W * NSTAGES * sizeof(int);
  const size_t CAND_BYTES = (size_t)NB * BEAM_W * BEAM_W * sizeof(int);
  const size_t BEST_BYTES = (size_t)NB * NSTAGES * sizeof(int);
  if (ws_size < M_BYTES + REM_BYTES + S_BYTES + CB2_BYTES + TUP_BYTES + CAND_BYTES + BEST_BYTES)
    return;

  char* ws = (char*)d_ws;
  float* Mbuf = (float*)ws;                    ws += M_BYTES;
  float* rem  = (float*)ws;                    ws += REM_BYTES;
  float* Srow = (float*)ws;                    ws += S_BYTES;
  float* cb2  = (float*)ws;                    ws += CB2_BYTES;
  int*   tup  = (int*)ws;                      ws += TUP_BYTES;
  int*   cand = (int*)ws;                      ws += CAND_BYTES;
  int*   best = (int*)ws;

  cb2_pw<<<SK / 256, 256, 0, stream>>>(cb, cb2);
  s0_pw<<<NB / 256, 256, 0, stream>>>(x, Srow);

  dim3 gg(SK / 128, NB / 128);
  gemm_seq<<<gg, 256, 0, stream>>>(x, cb, Mbuf);
  scan_top4<<<NB, 256, 0, stream>>>(Mbuf, Srow, cb2, tup, 0, 0, 1, tup, cand);

  for (int it = 0; it < NSTAGES - 1; ++it) {
    rem_pw<<<(NB * BEAM_W) / 256, 256, 0, stream>>>(x, cb, tup, it, rem, Srow);
    for (int c = 0; c < 4; ++c) {
      gemm_seq<<<gg, 256, 0, stream>>>(rem + (size_t)c * NB * D, cb, Mbuf);
      scan_top4<<<NB, 256, 0, stream>>>(Mbuf, Srow, cb2, tup, it, c * NB, 0, tup, cand);
    }
    mse_select<<<NB, 256, 0, stream>>>(x, cb, cand, it, tup, best);
  }

  zero_used<<<SK / 256, 256, 0, stream>>>(out + (size_t)NB * D);
  finalize_kernel<<<NB, 256, 0, stream>>>(x, cb, rv, best, tm, out);
}

// Round 10
// 2076.932 us; speedup vs baseline: 1.3731x; 1.0217x over previous
//
#include <hip/hip_runtime.h>
#include <math.h>

#define NSTAGES 4
#define NCB     1024
#define SK      4096   // NSTAGES*NCB
#define D       256
#define BEAM_W  4
#define NB      4096   // N samples
#define INFF    __builtin_huge_valf()

// ---------------- LLVM-vectorized reduce over 256 f32, VF=8, IC=4 (FROZEN - bit-exact vs ref)
template <typename F>
__device__ __forceinline__ float xw84(F v) {
  float r[32];
#pragma unroll
  for (int l = 0; l < 32; ++l) r[l] = v(l);
  for (int i = 32; i < 256; i += 32)
#pragma unroll
    for (int l = 0; l < 32; ++l) r[l] = __fadd_rn(r[l], v(i + l));
  float w[8];
#pragma unroll
  for (int j = 0; j < 8; ++j)
    w[j] = __fadd_rn(__fadd_rn(__fadd_rn(r[j], r[8 + j]), r[16 + j]), r[24 + j]);
  float s0 = __fadd_rn(w[0], w[4]);
  float s1 = __fadd_rn(w[1], w[5]);
  float s2 = __fadd_rn(w[2], w[6]);
  float s3 = __fadd_rn(w[3], w[7]);
  float t0 = __fadd_rn(s0, s2);
  float t1 = __fadd_rn(s1, s3);
  return __fadd_rn(t0, t1);
}

// ---------------- sorted top-4 insertion under strict (key, idx) lex order (FROZEN ties)
__device__ __forceinline__ void ins4(float k, int id, float bk[4], int bi[4]) {
  if (k < bk[3] || (k == bk[3] && id < bi[3])) {
    bk[3] = k; bi[3] = id;
#pragma unroll
    for (int s = 3; s >= 1; --s) {
      if (bk[s] < bk[s - 1] || (bk[s] == bk[s - 1] && bi[s] < bi[s - 1])) {
        float tk = bk[s]; bk[s] = bk[s - 1]; bk[s - 1] = tk;
        int   ti = bi[s]; bi[s] = bi[s - 1]; bi[s - 1] = ti;
      }
    }
  }
}

// ---------------- cb2[j] = sum(cb[j]**2)
__global__ __launch_bounds__(256) void cb2_pw(const float* __restrict__ cb,
                                              float* __restrict__ cb2) {
  int row = blockIdx.x * 256 + threadIdx.x;
  if (row >= SK) return;
  const float* c = cb + (size_t)row * D;
  cb2[row] = xw84([&](int d) { float t = c[d]; return __fmul_rn(t, t); });
}

// ---------------- Srow[s] = sum(x[s]**2)
__global__ __launch_bounds__(256) void s0_pw(const float* __restrict__ x,
                                             float* __restrict__ Srow) {
  int row = blockIdx.x * 256 + threadIdx.x;
  if (row >= NB) return;
  const float* xr = x + (size_t)row * D;
  Srow[row] = xw84([&](int d) { float t = xr[d]; return __fmul_rn(t, t); });
}

// ---------------- remainder rows + their sum-of-squares (FROZEN numerics)
__global__ __launch_bounds__(256) void rem_pw(const float* __restrict__ x,
                                              const float* __restrict__ cb,
                                              const int* __restrict__ tuples,
                                              int it,
                                              float* __restrict__ rem,
                                              float* __restrict__ Srow) {
  int row = blockIdx.x * 256 + threadIdx.x;
  if (row >= NB * BEAM_W) return;
  int s = row >> 2;
  int slot = tuples[row * NSTAGES + it];
  const float* xr = x + (size_t)s * D;
  const float* cr = cb + (size_t)slot * D;
  const float mf = (float)(it + 1);
  float* rr = rem + (size_t)row * D;
  for (int d = 0; d < D; ++d)
    rr[d] = __fsub_rn(xr[d], __fmul_rn(mf, cr[d]));
  Srow[row] = xw84([&](int d) {
    float t = __fsub_rn(xr[d], __fmul_rn(mf, cr[d]));
    return __fmul_rn(t, t);
  });
}

// ---------------- fused GEMM + key + ban + per-block top-4.
// M[r,j] = strict ascending-k fmaf chain (FROZEN). key = fl(fl(S - fl(2M)) + cb2) (FROZEN).
// Per (row, 128-col block): 4 smallest (key, gcol) lex pairs -> pk/pidx.
__global__ __launch_bounds__(256) void gemm_fused(
    const float* __restrict__ A, const float* __restrict__ B,
    const float* __restrict__ Srow, const float* __restrict__ cb2,
    const int* __restrict__ tuples, int it, int isStep0, int nrows,
    float* __restrict__ pk, int* __restrict__ pidx) {
  __shared__ __align__(16) char smem[49152];
  float (*As)[128] = (float (*)[128])smem;           // k-major, 16 KB
  float (*Bs)[128] = (float (*)[128])(smem + 16384); // 16 KB
  const int tx = threadIdx.x & 15;
  const int ty = threadIdx.x >> 4;
  const int row0 = blockIdx.y * 128;
  const int col0 = blockIdx.x * 128;
  float acc[8][8];
#pragma unroll
  for (int i = 0; i < 8; ++i)
#pragma unroll
    for (int j = 0; j < 8; ++j) acc[i][j] = 0.0f;

  for (int kt = 0; kt < D; kt += 32) {
#pragma unroll
    for (int l = 0; l < 4; ++l) {
      int t  = threadIdx.x + l * 256;   // 0..1023
      int r  = t & 127;
      int kc = (t >> 7) * 4;
      float4 va = *(const float4*)&A[(size_t)(row0 + r) * D + kt + kc];
      As[kc + 0][r] = va.x; As[kc + 1][r] = va.y; As[kc + 2][r] = va.z; As[kc + 3][r] = va.w;
      float4 vb = *(const float4*)&B[(size_t)(col0 + r) * D + kt + kc];
      Bs[kc + 0][r] = vb.x; Bs[kc + 1][r] = vb.y; Bs[kc + 2][r] = vb.z; Bs[kc + 3][r] = vb.w;
    }
    __syncthreads();
#pragma unroll 8
    for (int k = 0; k < 32; ++k) {   // ascending k only — do not reorder
      float a[8], b[8];
      *(float4*)&a[0] = *(const float4*)&As[k][ty * 4];
      *(float4*)&a[4] = *(const float4*)&As[k][64 + ty * 4];
      *(float4*)&b[0] = *(const float4*)&Bs[k][tx * 4];
      *(float4*)&b[4] = *(const float4*)&Bs[k][64 + tx * 4];
#pragma unroll
      for (int i = 0; i < 8; ++i)
#pragma unroll
        for (int j = 0; j < 8; ++j)
          acc[i][j] = __fmaf_rn(a[i], b[j], acc[i][j]);
    }
    __syncthreads();
  }

  // ---- epilogue: keys + per-thread top-4 per row, then merge across tx
  float (*tkey)[16][4] = (float (*)[16][4])smem;                               // 32 KB
  unsigned short (*tidx)[16][4] = (unsigned short (*)[16][4])(smem + 32768);   // 16 KB
#pragma unroll
  for (int i = 0; i < 8; ++i) {
    int lrow = (i & 3) + ((i >> 2) * 64) + ty * 4;
    int grow = row0 + lrow;
    float S = Srow[grow];
    int banned = 0;
    if (!isStep0)
      for (int a = 0; a <= it; ++a) banned |= 1 << (tuples[grow * NSTAGES + a] >> 10);
    float bk[4] = {INFF, INFF, INFF, INFF};
    int   bi[4] = {0x7fffffff, 0x7fffffff, 0x7fffffff, 0x7fffffff};
#pragma unroll
    for (int j = 0; j < 8; ++j) {
      int lcol = (j & 3) + ((j >> 2) * 64) + tx * 4;
      int gcol = col0 + lcol;
      float key = ((banned >> (gcol >> 10)) & 1)
                      ? INFF
                      : __fadd_rn(__fsub_rn(S, __fmul_rn(2.0f, acc[i][j])), cb2[gcol]);
      ins4(key, lcol, bk, bi);
    }
#pragma unroll
    for (int s = 0; s < 4; ++s) {
      tkey[lrow][tx][s] = bk[s];
      tidx[lrow][tx][s] = (unsigned short)bi[s];
    }
  }
  __syncthreads();
  if (threadIdx.x < 128) {
    int lrow = threadIdx.x;
    int grow = row0 + lrow;
    float bk[4] = {INFF, INFF, INFF, INFF};
    int   bi[4] = {0x7fffffff, 0x7fffffff, 0x7fffffff, 0x7fffffff};
    for (int t = 0; t < 16; ++t)
#pragma unroll
      for (int s = 0; s < 4; ++s)
        ins4(tkey[lrow][t][s], (int)tidx[lrow][t][s], bk, bi);
    size_t base = ((size_t)blockIdx.x * nrows + grow) * 4;
#pragma unroll
    for (int s = 0; s < 4; ++s) {
      pk[base + s]   = bk[s];
      pidx[base + s] = col0 + bi[s];
    }
  }
}

// ---------------- merge 32 per-block top-4 lists per row -> global top-4 (exact lex)
__global__ __launch_bounds__(256) void reduce_top4(
    const float* __restrict__ pk, const int* __restrict__ pidx,
    int nrows, int isStep0,
    int* __restrict__ tup, int* __restrict__ cand) {
  int r = blockIdx.x * 256 + threadIdx.x;
  if (r >= nrows) return;
  float bk[4] = {INFF, INFF, INFF, INFF};
  int   bi[4] = {0x7fffffff, 0x7fffffff, 0x7fffffff, 0x7fffffff};
  for (int cb = 0; cb < SK / 128; ++cb) {
    size_t base = ((size_t)cb * nrows + r) * 4;
    float4 k4 = *(const float4*)&pk[base];
    int4   i4 = *(const int4*)&pidx[base];
    ins4(k4.x, i4.x, bk, bi);
    ins4(k4.y, i4.y, bk, bi);
    ins4(k4.z, i4.z, bk, bi);
    ins4(k4.w, i4.w, bk, bi);
  }
  if (isStep0) {
#pragma unroll
    for (int s = 0; s < 4; ++s) tup[(r * BEAM_W + s) * NSTAGES + 0] = bi[s];
  } else {
#pragma unroll
    for (int s = 0; s < 4; ++s) cand[r * BEAM_W + s] = bi[s];
  }
}

// ---------------- expand 16 tuples, mse via VF8/IC4 reduce, select (FROZEN numerics)
__global__ __launch_bounds__(256) void mse_select(const float* __restrict__ x,
                                                  const float* __restrict__ cb,
                                                  const int* __restrict__ cand,
                                                  int it,
                                                  int* __restrict__ tuples,
                                                  int* __restrict__ best) {
  const int s = blockIdx.x, tid = threadIdx.x;
  const int wv = tid >> 6, lane = tid & 63;
  __shared__ float buf[4][256];
  __shared__ float rr[4][32];
  __shared__ float msek[16];
  __shared__ int   primes[16][NSTAGES];
  const int L = it + 2;

  for (int pi = 0; pi < 4; ++pi) {
    const int p = wv * 4 + pi;
    const int b = p >> 2, c = p & 3;
    int tpl[NSTAGES];
    for (int a = 0; a < NSTAGES; ++a) tpl[a] = tuples[(s * BEAM_W + b) * NSTAGES + a];
    tpl[it + 1] = cand[(s * BEAM_W + b) * BEAM_W + c];
    if (lane == 0)
      for (int a = 0; a < NSTAGES; ++a) primes[p][a] = tpl[a];
    for (int d = lane; d < D; d += 64) {
      float q = cb[(size_t)tpl[0] * D + d];
      for (int a = 1; a < L; ++a) q = __fadd_rn(q, cb[(size_t)tpl[a] * D + d]);
      float v = __fsub_rn(x[(size_t)s * D + d], q);
      buf[wv][d] = __fmul_rn(v, v);
    }
    __syncthreads();
    if (lane < 32) {
      float r = buf[wv][lane];
      for (int i = 32; i < 256; i += 32) r = __fadd_rn(r, buf[wv][i + lane]);
      rr[wv][lane] = r;
    }
    __syncthreads();
    if (lane == 0) {
      float w[8];
#pragma unroll
      for (int j = 0; j < 8; ++j)
        w[j] = __fadd_rn(__fadd_rn(__fadd_rn(rr[wv][j], rr[wv][8 + j]), rr[wv][16 + j]),
                         rr[wv][24 + j]);
      float s0 = __fadd_rn(w[0], w[4]);
      float s1 = __fadd_rn(w[1], w[5]);
      float s2 = __fadd_rn(w[2], w[6]);
      float s3 = __fadd_rn(w[3], w[7]);
      float t0 = __fadd_rn(s0, s2);
      float t1 = __fadd_rn(s1, s3);
      float S2 = __fadd_rn(t0, t1);
      msek[p] = __fmul_rn(S2, 0.00390625f);  // /256 exact
    }
    __syncthreads();
  }

  if (tid == 0) {
    if (it < NSTAGES - 2) {
      bool taken[16] = {false};
      int  newt[BEAM_W][NSTAGES];
      for (int r = 0; r < BEAM_W; ++r) {
        int bp = -1; float bk = 0.0f;
        for (int p = 0; p < 16; ++p) {
          if (taken[p]) continue;
          if (bp < 0 || msek[p] < bk) { bk = msek[p]; bp = p; }  // strict <: lowest p wins ties
        }
        taken[bp] = true;
        for (int a = 0; a < NSTAGES; ++a) newt[r][a] = primes[bp][a];
      }
      for (int r = 0; r < BEAM_W; ++r)
        for (int a = 0; a < NSTAGES; ++a) tuples[(s * BEAM_W + r) * NSTAGES + a] = newt[r][a];
    } else {
      int bp = 0; float bk = msek[0];
      for (int p = 1; p < 16; ++p)
        if (msek[p] < bk) { bk = msek[p]; bp = p; }   // argmin: first lowest
      for (int a = 0; a < NSTAGES; ++a) best[s * NSTAGES + a] = primes[bp][a];
    }
  }
}

// ---------------- zero the 'used' region of d_out
__global__ void zero_used(float* __restrict__ u) {
  int t = blockIdx.x * 256 + threadIdx.x;
  if (t < SK) u[t] = 0.0f;
}

// ---------------- epilogue: nsvq (or quantized) + used bitmap
__global__ __launch_bounds__(256) void finalize_kernel(const float* __restrict__ x,
                                                       const float* __restrict__ cb,
                                                       const float* __restrict__ rvec,
                                                       const int* __restrict__ best,
                                                       const int* __restrict__ tmode,
                                                       float* __restrict__ out) {
  const int i = blockIdx.x;
  const int t = threadIdx.x;
  __shared__ double s1[256], s2[256];
  const int b0 = best[i * 4 + 0], b1 = best[i * 4 + 1];
  const int b2 = best[i * 4 + 2], b3 = best[i * 4 + 3];
  float q = ((cb[(size_t)b0 * D + t] + cb[(size_t)b1 * D + t]) + cb[(size_t)b2 * D + t]) +
            cb[(size_t)b3 * D + t];
  float xv = x[(size_t)i * D + t];
  float rv = rvec[(size_t)i * D + t];
  float df = xv - q;
  s1[t] = (double)df * (double)df;
  s2[t] = (double)rv * (double)rv;
  __syncthreads();
  for (int off = 128; off; off >>= 1) {
    if (t < off) { s1[t] += s1[t + off]; s2[t] += s2[t + off]; }
    __syncthreads();
  }
  float nh = sqrtf((float)s1[0]);
  float nr = sqrtf((float)s2[0]);
  float ratio = nh / nr + 1e-12f;
  out[(size_t)i * D + t] = (*tmode != 0) ? (xv + ratio * rv) : q;
  if (t < 4) out[(size_t)NB * D + best[i * 4 + t]] = 1.0f;
}

// ----------------------------------------------------------------
extern "C" void kernel_launch(void* const* d_in, const int* in_sizes, int n_in,
                              void* d_out, int out_size, void* d_ws, size_t ws_size,
                              hipStream_t stream) {
  const float* x   = (const float*)d_in[0];
  const float* cb  = (const float*)d_in[1];
  const float* rv  = (const float*)d_in[2];
  const int*   tm  = (const int*)d_in[3];
  float*       out = (float*)d_out;

  const size_t M_BYTES    = (size_t)NB * SK * sizeof(float);           // holds pk + pidx
  const size_t REM_BYTES  = (size_t)NB * BEAM_W * D * sizeof(float);
  const size_t S_BYTES    = (size_t)NB * BEAM_W * sizeof(float);
  const size_t CB2_BYTES  = (size_t)SK * sizeof(float);
  const size_t TUP_BYTES  = (size_t)NB * BEAM_W * NSTAGES * sizeof(int);
  const size_t CAND_BYTES = (size_t)NB * BEAM_W * BEAM_W * sizeof(int);
  const size_t BEST_BYTES = (size_t)NB * NSTAGES * sizeof(int);
  if (ws_size < M_BYTES + REM_BYTES + S_BYTES + CB2_BYTES + TUP_BYTES + CAND_BYTES + BEST_BYTES)
    return;

  char* ws = (char*)d_ws;
  float* Mbuf = (float*)ws;                    ws += M_BYTES;
  float* rem  = (float*)ws;                    ws += REM_BYTES;
  float* Srow = (float*)ws;                    ws += S_BYTES;
  float* cb2  = (float*)ws;                    ws += CB2_BYTES;
  int*   tup  = (int*)ws;                      ws += TUP_BYTES;
  int*   cand = (int*)ws;                      ws += CAND_BYTES;
  int*   best = (int*)ws;

  // carve partial-top4 buffers from Mbuf (max 32 cblk * 16384 rows * 4 = 8 MB each)
  float* pk   = Mbuf;
  int*   pidx = (int*)(Mbuf + (size_t)(SK / 128) * NB * BEAM_W * 4);

  cb2_pw<<<SK / 256, 256, 0, stream>>>(cb, cb2);
  s0_pw<<<NB / 256, 256, 0, stream>>>(x, Srow);

  // step 0: dists(x) over all samples, fused top-4
  gemm_fused<<<dim3(SK / 128, NB / 128), 256, 0, stream>>>(x, cb, Srow, cb2, tup, 0, 1, NB,
                                                           pk, pidx);
  reduce_top4<<<NB / 256, 256, 0, stream>>>(pk, pidx, NB, 1, tup, cand);

  for (int it = 0; it < NSTAGES - 1; ++it) {
    rem_pw<<<(NB * BEAM_W) / 256, 256, 0, stream>>>(x, cb, tup, it, rem, Srow);
    gemm_fused<<<dim3(SK / 128, (NB * BEAM_W) / 128), 256, 0, stream>>>(
        rem, cb, Srow, cb2, tup, it, 0, NB * BEAM_W, pk, pidx);
    reduce_top4<<<(NB * BEAM_W) / 256, 256, 0, stream>>>(pk, pidx, NB * BEAM_W, 0, tup, cand);
    mse_select<<<NB, 256, 0, stream>>>(x, cb, cand, it, tup, best);
  }

  zero_used<<<SK / 256, 256, 0, stream>>>(out + (size_t)NB * D);
  finalize_kernel<<<NB, 256, 0, stream>>>(x, cb, rv, best, tm, out);
}

// Round 11
// 1726.146 us; speedup vs baseline: 1.6522x; 1.2032x over previous
//
#include <hip/hip_runtime.h>
#include <math.h>

#define NSTAGES 4
#define NCB     1024
#define SK      4096   // NSTAGES*NCB
#define D       256
#define BEAM_W  4
#define NB      4096   // N samples
#define INFF    __builtin_huge_valf()
#define RB      128    // gemm rows per block
#define CBL     256    // gemm cols per block
#define NCBLK   (SK / CBL)   // 16 col-blocks

typedef unsigned long long u64;

// ---------------- LLVM-vectorized reduce over 256 f32, VF=8, IC=4 (FROZEN - bit-exact vs ref)
template <typename F>
__device__ __forceinline__ float xw84(F v) {
  float r[32];
#pragma unroll
  for (int l = 0; l < 32; ++l) r[l] = v(l);
  for (int i = 32; i < 256; i += 32)
#pragma unroll
    for (int l = 0; l < 32; ++l) r[l] = __fadd_rn(r[l], v(i + l));
  float w[8];
#pragma unroll
  for (int j = 0; j < 8; ++j)
    w[j] = __fadd_rn(__fadd_rn(__fadd_rn(r[j], r[8 + j]), r[16 + j]), r[24 + j]);
  float s0 = __fadd_rn(w[0], w[4]);
  float s1 = __fadd_rn(w[1], w[5]);
  float s2 = __fadd_rn(w[2], w[6]);
  float s3 = __fadd_rn(w[3], w[7]);
  float t0 = __fadd_rn(s0, s2);
  float t1 = __fadd_rn(s1, s3);
  return __fadd_rn(t0, t1);
}

// ---------------- sorted ascending top-4 insert on packed u64 (keybits<<32 | idx).
// Keys are ~250 (always > 0) so float order == bit order; u64 order == lex (key, idx). FROZEN ties.
__device__ __forceinline__ void ins4u(u64 v, u64 b[4]) {
  if (v < b[3]) {
    b[3] = v;
    if (b[3] < b[2]) { u64 t = b[2]; b[2] = b[3]; b[3] = t; }
    if (b[2] < b[1]) { u64 t = b[1]; b[1] = b[2]; b[2] = t; }
    if (b[1] < b[0]) { u64 t = b[0]; b[0] = b[1]; b[1] = t; }
  }
}

// ---------------- cb2[j] = sum(cb[j]**2)
__global__ __launch_bounds__(256) void cb2_pw(const float* __restrict__ cb,
                                              float* __restrict__ cb2) {
  int row = blockIdx.x * 256 + threadIdx.x;
  if (row >= SK) return;
  const float* c = cb + (size_t)row * D;
  cb2[row] = xw84([&](int d) { float t = c[d]; return __fmul_rn(t, t); });
}

// ---------------- Srow[s] = sum(x[s]**2)
__global__ __launch_bounds__(256) void s0_pw(const float* __restrict__ x,
                                             float* __restrict__ Srow) {
  int row = blockIdx.x * 256 + threadIdx.x;
  if (row >= NB) return;
  const float* xr = x + (size_t)row * D;
  Srow[row] = xw84([&](int d) { float t = xr[d]; return __fmul_rn(t, t); });
}

// ---------------- Srow for remainder rows (FROZEN numerics); rem itself is not materialized
__global__ __launch_bounds__(256) void srow_pw(const float* __restrict__ x,
                                               const float* __restrict__ cb,
                                               const int* __restrict__ tuples,
                                               int it,
                                               float* __restrict__ Srow) {
  int row = blockIdx.x * 256 + threadIdx.x;
  if (row >= NB * BEAM_W) return;
  int s = row >> 2;
  int slot = tuples[row * NSTAGES + it];
  const float* xr = x + (size_t)s * D;
  const float* cr = cb + (size_t)slot * D;
  const float mf = (float)(it + 1);
  Srow[row] = xw84([&](int d) {
    float t = __fsub_rn(xr[d], __fmul_rn(mf, cr[d]));
    return __fmul_rn(t, t);
  });
}

// ---------------- fused GEMM (128x256 block, 8x16 thread tile) + key + ban + per-block top-4.
// A-row elements computed on the fly: fl(x - fl(m*c_slot)) (bit-identical to srow_pw's rem).
// M = strict ascending-k fmaf chain (FROZEN). key = fl(fl(S - fl(2M)) + cb2) (FROZEN).
__global__ __launch_bounds__(256, 2) void gemm_fused(
    const float* __restrict__ x, const float* __restrict__ cbk,
    const float* __restrict__ Srow, const float* __restrict__ cb2,
    const int* __restrict__ tuples, int it, int isStep0, int nrows,
    u64* __restrict__ pki) {
  __shared__ __align__(16) char smem[66560];
  float (*As)[RB]  = (float (*)[RB])smem;            // [32][128] k-major, 16 KB
  float (*Bs)[CBL] = (float (*)[CBL])(smem + 16384); // [32][256] k-major, 32 KB
  u64* tki = (u64*)smem;                             // [128][65] aliased after K-loop, 65 KB
  const int tid = threadIdx.x;
  const int tx = tid & 15, ty = tid >> 4;
  const int row0 = blockIdx.y * RB;
  const int col0 = blockIdx.x * CBL;
  const float mf = (float)(it + 1);

  // staging sources: thread stages A-row (tid&127) k-chunks {tid>>7 + 2l}, B-row (col0+tid) all chunks
  const int ar  = tid & 127;
  const int grA = row0 + ar;
  const float* xrow;
  const float* crowA = nullptr;
  if (isStep0) {
    xrow = x + (size_t)grA * D;
  } else {
    xrow  = x + (size_t)(grA >> 2) * D;
    crowA = cbk + (size_t)tuples[grA * NSTAGES + it] * D;
  }
  const float* crowB = cbk + (size_t)(col0 + tid) * D;

  float acc[8][16];
#pragma unroll
  for (int i = 0; i < 8; ++i)
#pragma unroll
    for (int j = 0; j < 16; ++j) acc[i][j] = 0.0f;

  for (int kt = 0; kt < D; kt += 32) {
#pragma unroll
    for (int l = 0; l < 4; ++l) {
      int kc = ((tid >> 7) + 2 * l) * 4;
      float4 v = *(const float4*)&xrow[kt + kc];
      if (!isStep0) {
        float4 c = *(const float4*)&crowA[kt + kc];
        v.x = __fsub_rn(v.x, __fmul_rn(mf, c.x));
        v.y = __fsub_rn(v.y, __fmul_rn(mf, c.y));
        v.z = __fsub_rn(v.z, __fmul_rn(mf, c.z));
        v.w = __fsub_rn(v.w, __fmul_rn(mf, c.w));
      }
      As[kc + 0][ar] = v.x; As[kc + 1][ar] = v.y; As[kc + 2][ar] = v.z; As[kc + 3][ar] = v.w;
    }
#pragma unroll
    for (int l = 0; l < 8; ++l) {
      int kc = l * 4;
      float4 v = *(const float4*)&crowB[kt + kc];
      Bs[kc + 0][tid] = v.x; Bs[kc + 1][tid] = v.y; Bs[kc + 2][tid] = v.z; Bs[kc + 3][tid] = v.w;
    }
    __syncthreads();
#pragma unroll 8
    for (int k = 0; k < 32; ++k) {   // ascending k only — do not reorder
      float a[8], b[16];
      *(float4*)&a[0]  = *(const float4*)&As[k][ty * 4];
      *(float4*)&a[4]  = *(const float4*)&As[k][64 + ty * 4];
      *(float4*)&b[0]  = *(const float4*)&Bs[k][tx * 4];
      *(float4*)&b[4]  = *(const float4*)&Bs[k][64 + tx * 4];
      *(float4*)&b[8]  = *(const float4*)&Bs[k][128 + tx * 4];
      *(float4*)&b[12] = *(const float4*)&Bs[k][192 + tx * 4];
#pragma unroll
      for (int i = 0; i < 8; ++i)
#pragma unroll
        for (int j = 0; j < 16; ++j)
          acc[i][j] = __fmaf_rn(a[i], b[j], acc[i][j]);
    }
    __syncthreads();
  }

  // ---- phase 1: keys + per-thread top-4 per row -> tki[lrow][tx*4+s] (stride 65 u64)
#pragma unroll
  for (int i = 0; i < 8; ++i) {
    int lrow = (i & 3) + ((i >> 2) * 64) + ty * 4;
    int grow = row0 + lrow;
    float S = Srow[grow];
    int banned = 0;
    if (!isStep0)
      for (int a = 0; a <= it; ++a) banned |= 1 << (tuples[grow * NSTAGES + a] >> 10);
    u64 b4[4] = {~0ULL, ~0ULL, ~0ULL, ~0ULL};
#pragma unroll
    for (int j = 0; j < 16; ++j) {
      int gcol = col0 + (j & 3) + ((j >> 2) * 64) + tx * 4;
      float key = ((banned >> (gcol >> 10)) & 1)
                      ? INFF
                      : __fadd_rn(__fsub_rn(S, __fmul_rn(2.0f, acc[i][j])), cb2[gcol]);
      ins4u(((u64)__float_as_uint(key) << 32) | (unsigned)gcol, b4);
    }
#pragma unroll
    for (int s = 0; s < 4; ++s) tki[(size_t)lrow * 65 + tx * 4 + s] = b4[s];
  }
  __syncthreads();

  // ---- phase 2: merge 16 lists per row (stride-65 padding -> max 4-way conflicts)
  if (tid < RB) {
    u64 b4[4] = {~0ULL, ~0ULL, ~0ULL, ~0ULL};
    for (int t = 0; t < 16; ++t)
#pragma unroll
      for (int s = 0; s < 4; ++s) ins4u(tki[(size_t)tid * 65 + t * 4 + s], b4);
    size_t base = ((size_t)blockIdx.x * nrows + row0 + tid) * 4;
#pragma unroll
    for (int s = 0; s < 4; ++s) pki[base + s] = b4[s];
  }
}

// ---------------- merge 16 per-block top-4 lists per row -> global top-4 (exact lex)
__global__ __launch_bounds__(256) void reduce_top4(
    const u64* __restrict__ pki, int nrows, int isStep0,
    int* __restrict__ tup, int* __restrict__ cand) {
  int r = blockIdx.x * 256 + threadIdx.x;
  if (r >= nrows) return;
  u64 b4[4] = {~0ULL, ~0ULL, ~0ULL, ~0ULL};
  for (int cblk = 0; cblk < NCBLK; ++cblk) {
    size_t base = ((size_t)cblk * nrows + r) * 4;
    ins4u(pki[base + 0], b4);
    ins4u(pki[base + 1], b4);
    ins4u(pki[base + 2], b4);
    ins4u(pki[base + 3], b4);
  }
  if (isStep0) {
#pragma unroll
    for (int s = 0; s < 4; ++s)
      tup[(r * BEAM_W + s) * NSTAGES + 0] = (int)(b4[s] & 0xFFFFFFFFULL);
  } else {
#pragma unroll
    for (int s = 0; s < 4; ++s)
      cand[r * BEAM_W + s] = (int)(b4[s] & 0xFFFFFFFFULL);
  }
}

// ---------------- expand 16 tuples, mse via VF8/IC4 reduce, select (FROZEN numerics)
__global__ __launch_bounds__(256) void mse_select(const float* __restrict__ x,
                                                  const float* __restrict__ cb,
                                                  const int* __restrict__ cand,
                                                  int it,
                                                  int* __restrict__ tuples,
                                                  int* __restrict__ best) {
  const int s = blockIdx.x, tid = threadIdx.x;
  const int wv = tid >> 6, lane = tid & 63;
  __shared__ float buf[4][256];
  __shared__ float rr[4][32];
  __shared__ float msek[16];
  __shared__ int   primes[16][NSTAGES];
  const int L = it + 2;

  for (int pi = 0; pi < 4; ++pi) {
    const int p = wv * 4 + pi;
    const int b = p >> 2, c = p & 3;
    int tpl[NSTAGES];
    for (int a = 0; a < NSTAGES; ++a) tpl[a] = tuples[(s * BEAM_W + b) * NSTAGES + a];
    tpl[it + 1] = cand[(s * BEAM_W + b) * BEAM_W + c];
    if (lane == 0)
      for (int a = 0; a < NSTAGES; ++a) primes[p][a] = tpl[a];
    for (int d = lane; d < D; d += 64) {
      float q = cb[(size_t)tpl[0] * D + d];
      for (int a = 1; a < L; ++a) q = __fadd_rn(q, cb[(size_t)tpl[a] * D + d]);
      float v = __fsub_rn(x[(size_t)s * D + d], q);
      buf[wv][d] = __fmul_rn(v, v);
    }
    __syncthreads();
    if (lane < 32) {
      float r = buf[wv][lane];
      for (int i = 32; i < 256; i += 32) r = __fadd_rn(r, buf[wv][i + lane]);
      rr[wv][lane] = r;
    }
    __syncthreads();
    if (lane == 0) {
      float w[8];
#pragma unroll
      for (int j = 0; j < 8; ++j)
        w[j] = __fadd_rn(__fadd_rn(__fadd_rn(rr[wv][j], rr[wv][8 + j]), rr[wv][16 + j]),
                         rr[wv][24 + j]);
      float s0 = __fadd_rn(w[0], w[4]);
      float s1 = __fadd_rn(w[1], w[5]);
      float s2 = __fadd_rn(w[2], w[6]);
      float s3 = __fadd_rn(w[3], w[7]);
      float t0 = __fadd_rn(s0, s2);
      float t1 = __fadd_rn(s1, s3);
      float S2 = __fadd_rn(t0, t1);
      msek[p] = __fmul_rn(S2, 0.00390625f);  // /256 exact
    }
    __syncthreads();
  }

  if (tid == 0) {
    if (it < NSTAGES - 2) {
      bool taken[16] = {false};
      int  newt[BEAM_W][NSTAGES];
      for (int r = 0; r < BEAM_W; ++r) {
        int bp = -1; float bk = 0.0f;
        for (int p = 0; p < 16; ++p) {
          if (taken[p]) continue;
          if (bp < 0 || msek[p] < bk) { bk = msek[p]; bp = p; }  // strict <: lowest p wins ties
        }
        taken[bp] = true;
        for (int a = 0; a < NSTAGES; ++a) newt[r][a] = primes[bp][a];
      }
      for (int r = 0; r < BEAM_W; ++r)
        for (int a = 0; a < NSTAGES; ++a) tuples[(s * BEAM_W + r) * NSTAGES + a] = newt[r][a];
    } else {
      int bp = 0; float bk = msek[0];
      for (int p = 1; p < 16; ++p)
        if (msek[p] < bk) { bk = msek[p]; bp = p; }   // argmin: first lowest
      for (int a = 0; a < NSTAGES; ++a) best[s * NSTAGES + a] = primes[bp][a];
    }
  }
}

// ---------------- zero the 'used' region of d_out
__global__ void zero_used(float* __restrict__ u) {
  int t = blockIdx.x * 256 + threadIdx.x;
  if (t < SK) u[t] = 0.0f;
}

// ---------------- epilogue: nsvq (or quantized) + used bitmap
__global__ __launch_bounds__(256) void finalize_kernel(const float* __restrict__ x,
                                                       const float* __restrict__ cb,
                                                       const float* __restrict__ rvec,
                                                       const int* __restrict__ best,
                                                       const int* __restrict__ tmode,
                                                       float* __restrict__ out) {
  const int i = blockIdx.x;
  const int t = threadIdx.x;
  __shared__ double s1[256], s2[256];
  const int b0 = best[i * 4 + 0], b1 = best[i * 4 + 1];
  const int b2 = best[i * 4 + 2], b3 = best[i * 4 + 3];
  float q = ((cb[(size_t)b0 * D + t] + cb[(size_t)b1 * D + t]) + cb[(size_t)b2 * D + t]) +
            cb[(size_t)b3 * D + t];
  float xv = x[(size_t)i * D + t];
  float rv = rvec[(size_t)i * D + t];
  float df = xv - q;
  s1[t] = (double)df * (double)df;
  s2[t] = (double)rv * (double)rv;
  __syncthreads();
  for (int off = 128; off; off >>= 1) {
    if (t < off) { s1[t] += s1[t + off]; s2[t] += s2[t + off]; }
    __syncthreads();
  }
  float nh = sqrtf((float)s1[0]);
  float nr = sqrtf((float)s2[0]);
  float ratio = nh / nr + 1e-12f;
  out[(size_t)i * D + t] = (*tmode != 0) ? (xv + ratio * rv) : q;
  if (t < 4) out[(size_t)NB * D + best[i * 4 + t]] = 1.0f;
}

// ----------------------------------------------------------------
extern "C" void kernel_launch(void* const* d_in, const int* in_sizes, int n_in,
                              void* d_out, int out_size, void* d_ws, size_t ws_size,
                              hipStream_t stream) {
  const float* x   = (const float*)d_in[0];
  const float* cb  = (const float*)d_in[1];
  const float* rv  = (const float*)d_in[2];
  const int*   tm  = (const int*)d_in[3];
  float*       out = (float*)d_out;

  const size_t PKI_BYTES  = (size_t)NCBLK * NB * BEAM_W * 4 * sizeof(u64);  // 8.4 MB
  const size_t S_BYTES    = (size_t)NB * BEAM_W * sizeof(float);
  const size_t CB2_BYTES  = (size_t)SK * sizeof(float);
  const size_t TUP_BYTES  = (size_t)NB * BEAM_W * NSTAGES * sizeof(int);
  const size_t CAND_BYTES = (size_t)NB * BEAM_W * BEAM_W * sizeof(int);
  const size_t BEST_BYTES = (size_t)NB * NSTAGES * sizeof(int);
  if (ws_size < PKI_BYTES + S_BYTES + CB2_BYTES + TUP_BYTES + CAND_BYTES + BEST_BYTES) return;

  char* ws = (char*)d_ws;
  u64*   pki  = (u64*)ws;                      ws += PKI_BYTES;
  float* Srow = (float*)ws;                    ws += S_BYTES;
  float* cb2  = (float*)ws;                    ws += CB2_BYTES;
  int*   tup  = (int*)ws;                      ws += TUP_BYTES;
  int*   cand = (int*)ws;                      ws += CAND_BYTES;
  int*   best = (int*)ws;

  cb2_pw<<<SK / 256, 256, 0, stream>>>(cb, cb2);
  s0_pw<<<NB / 256, 256, 0, stream>>>(x, Srow);

  // step 0: dists(x), fused top-4
  gemm_fused<<<dim3(NCBLK, NB / RB), 256, 0, stream>>>(x, cb, Srow, cb2, tup, 0, 1, NB, pki);
  reduce_top4<<<NB / 256, 256, 0, stream>>>(pki, NB, 1, tup, cand);

  for (int it = 0; it < NSTAGES - 1; ++it) {
    srow_pw<<<(NB * BEAM_W) / 256, 256, 0, stream>>>(x, cb, tup, it, Srow);
    gemm_fused<<<dim3(NCBLK, (NB * BEAM_W) / RB), 256, 0, stream>>>(
        x, cb, Srow, cb2, tup, it, 0, NB * BEAM_W, pki);
    reduce_top4<<<(NB * BEAM_W) / 256, 256, 0, stream>>>(pki, NB * BEAM_W, 0, tup, cand);
    mse_select<<<NB, 256, 0, stream>>>(x, cb, cand, it, tup, best);
  }

  zero_used<<<SK / 256, 256, 0, stream>>>(out + (size_t)NB * D);
  finalize_kernel<<<NB, 256, 0, stream>>>(x, cb, rv, best, tm, out);
}